// Round 7
// baseline (421.889 us; speedup 1.0000x reference)
//
#include <hip/hip_runtime.h>

// HMM scaled forward — separate streaming decode + register-resident MFMA scan.
//   BATCH=128, T=8192, N_STATES=128, EMIT=64
// decode_onehot: 256 MiB one-hot -> obsG[bg][n][t] bytes (1 MiB), HBM-bound.
// hmm_scan: one wave per (batch-group of 16, time-chunk of 16 + 8 warmup).
//   Permuted-K A fragments make the packed MFMA D-output directly the next
//   step's B-fragment — alpha never leaves registers; no barrier in loop.
//   Normalization telescoped (B-table pre-scaled by 64): 2-3 shfl reductions
//   per chunk. NCHUNK=512 -> 4096 waves = 4 waves/SIMD to hide MFMA latency.

#define BATCH 128
#define TLEN 8192
#define NS 128
#define EMIT 64
#define NCHUNK 512
#define CLEN (TLEN / NCHUNK)   // 16
#define WARM 8
#define BG 8                   // batch groups of 16
#define BSTR 132               // B-table row stride (bf16 elems)
#define LN64 4.158883083359672f

typedef __attribute__((ext_vector_type(8))) short short8;
typedef __attribute__((ext_vector_type(4))) float floatx4;
typedef __attribute__((ext_vector_type(4))) unsigned int uintx4;

__device__ __forceinline__ unsigned f2bf(float f) {
    return (__float_as_uint(f) + 0x8000u) >> 16;   // round-half-up to bf16
}

// decode 256 MiB one-hot -> obsG[bg][n][t] bytes (1 MiB); also zeroes out_ll
__global__ __launch_bounds__(256) void decode_onehot(
        const floatx4* __restrict__ x, unsigned char* __restrict__ obsG,
        float* __restrict__ out_ll) {
    if (blockIdx.x == 0 && threadIdx.x < BATCH) out_ll[threadIdx.x] = 0.f;
    int i = blockIdx.x * 256 + threadIdx.x;        // BATCH*TLEN*16 float4s
    floatx4 v = x[i];
    float s = v.x + v.y + v.z + v.w;
    if (s > 0.5f) {
        int e = (v.y > 0.5f) ? 1 : (v.z > 0.5f) ? 2 : (v.w > 0.5f) ? 3 : 0;
        int elem = (i << 2) + e;
        int row = elem >> 6;                       // b*TLEN + t
        int col = elem & 63;                       // emission symbol
        int b = row >> 13;
        int t = row & (TLEN - 1);
        obsG[(b >> 4) * (16 * TLEN) + (b & 15) * TLEN + t] = (unsigned char)col;
    }
}

__global__ __launch_bounds__(64) void hmm_scan(
        const float* __restrict__ Amat,
        const float* __restrict__ Bmat,
        const float* __restrict__ Ivec,
        const unsigned char* __restrict__ obsG,
        float* __restrict__ out_alpha,    // [BATCH][NS]
        float* __restrict__ out_ll)       // [BATCH]
{
    __shared__ unsigned short Bl[EMIT * BSTR];    // 16896 B: bf16(64*B)

    const int lane = threadIdx.x;
    const int n = lane & 15;              // batch within group (D col)
    const int q = lane >> 4;              // quad
    const int bg = blockIdx.x >> 9;       // / NCHUNK
    const int c = blockIdx.x & (NCHUNK - 1);
    const bool first = (c == 0);
    const bool lastc = (c == NCHUNK - 1);
    const int steps = first ? CLEN : (CLEN + WARM);
    const int t0 = first ? 0 : c * CLEN - WARM;

    // stage B scaled by 64 (exact pow2) as bf16, padded stride
    for (int i = lane; i < EMIT * NS; i += 64) {
        int e = i >> 7, col = i & (NS - 1);
        Bl[e * BSTR + col] = (unsigned short)f2bf(64.0f * Bmat[i]);
    }

    // this lane's obs bytes -> 6 dwords in registers (obsG row is batch n)
    const unsigned char* orow = obsG + bg * (16 * TLEN) + n * TLEN;
    unsigned ow[6];
    if (first) {                          // t0==0: 16 bytes, 16B aligned
        uintx4 a = *(const uintx4*)(orow);
        ow[0] = a.x; ow[1] = a.y; ow[2] = a.z; ow[3] = a.w;
        ow[4] = 0; ow[5] = 0;
    } else {                              // t0 = 16c-8 (8 mod 16): 8B + 16B
        uint2 a = *(const uint2*)(orow + t0);
        uintx4 b = *(const uintx4*)(orow + t0 + 8);
        ow[0] = a.x; ow[1] = a.y;
        ow[2] = b.x; ow[3] = b.y; ow[4] = b.z; ow[5] = b.w;
    }

    // A fragments with permuted K-order so packed D == next B-frag.
    // position u = 32kf + 8q + j  ->  state 32(u>>5)+16((u>>2)&1)+4((u>>3)&3)+(u&3)
    short8 af[8][4];
    #pragma unroll
    for (int mt = 0; mt < 8; ++mt)
        #pragma unroll
        for (int kf = 0; kf < 4; ++kf) {
            short8 v;
            #pragma unroll
            for (int j = 0; j < 8; ++j) {
                int u = 32 * kf + 8 * q + j;
                int sk = 32 * (u >> 5) + 16 * ((u >> 2) & 1)
                       + 4 * ((u >> 3) & 3) + (u & 3);
                v[j] = (short)f2bf(Amat[sk * NS + 16 * mt + n]);
            }
            af[mt][kf] = v;
        }
    __syncthreads();   // Bl ready

    // loop-carried packed alpha (bf16 pairs); init uniform for warmup
    unsigned pk[16];
    #pragma unroll
    for (int i = 0; i < 16; ++i) pk[i] = 0x3C003C00u;   // bf16(1/128) x2

    float s_pre = 1.0f, s_penult = 1.0f, s_end = 1.0f;

    for (int it = 0; it < steps; ++it) {
        floatx4 acc[8];
        if (first && it == 0) {
            // t==0: R := I (exact init), alpha0 = 64B[o] * I
            #pragma unroll
            for (int mt = 0; mt < 8; ++mt)
                acc[mt] = *(const floatx4*)(Ivec + 16 * mt + 4 * q);
        } else {
            short8 bf[4];
            #pragma unroll
            for (int kf = 0; kf < 4; ++kf) {
                uintx4 u4 = {pk[4 * kf], pk[4 * kf + 1], pk[4 * kf + 2], pk[4 * kf + 3]};
                bf[kf] = __builtin_bit_cast(short8, u4);
            }
            #pragma unroll
            for (int mt = 0; mt < 8; ++mt) {
                floatx4 a = {0.f, 0.f, 0.f, 0.f};
                #pragma unroll
                for (int kf = 0; kf < 4; ++kf)
                    a = __builtin_amdgcn_mfma_f32_16x16x32_bf16(af[mt][kf], bf[kf], a, 0, 0, 0);
                acc[mt] = a;
            }
        }

        // emission multiply (table holds 64*B)
        int o = (ow[it >> 2] >> ((it & 3) * 8)) & 0xFF;
        int eb = o * BSTR;
        #pragma unroll
        for (int mt = 0; mt < 8; ++mt) {
            const unsigned* ep = (const unsigned*)(Bl + eb + 16 * mt + 4 * q);
            unsigned d0 = ep[0], d1 = ep[1];
            acc[mt].x *= __uint_as_float(d0 << 16);
            acc[mt].y *= __uint_as_float(d0 & 0xFFFF0000u);
            acc[mt].z *= __uint_as_float(d1 << 16);
            acc[mt].w *= __uint_as_float(d1 & 0xFFFF0000u);
        }

        // rare per-chunk reductions (wave-uniform branch)
        bool need_red = (it == steps - 1) || (!first && it == WARM - 1) ||
                        (lastc && it == steps - 2);
        if (need_red) {
            float zz = 0.f;
            #pragma unroll
            for (int mt = 0; mt < 8; ++mt)
                zz += (acc[mt].x + acc[mt].y) + (acc[mt].z + acc[mt].w);
            zz += __shfl_xor(zz, 16, 64);
            zz += __shfl_xor(zz, 32, 64);      // S-bar per batch, all q-lanes
            if (it == steps - 1) s_end = zz;
            else if (lastc && it == steps - 2) s_penult = zz;
            else s_pre = zz;
        }

        if (lastc && it == steps - 1) {
            // alpha_f = alpha-bar_{T-1} / (64 * S-bar_{T-2})
            float inv = 1.0f / (64.0f * s_penult);
            #pragma unroll
            for (int mt = 0; mt < 8; ++mt) {
                floatx4 o4;
                o4.x = acc[mt].x * inv; o4.y = acc[mt].y * inv;
                o4.z = acc[mt].z * inv; o4.w = acc[mt].w * inv;
                *(floatx4*)(out_alpha + (bg * 16 + n) * NS + 16 * mt + 4 * q) = o4;
            }
        }

        // pack to bf16 pairs: directly forms next step's B-fragments
        #pragma unroll
        for (int mt = 0; mt < 8; ++mt) {
            unsigned u0 = __float_as_uint(acc[mt].x) + 0x8000u;
            unsigned u1 = __float_as_uint(acc[mt].y) + 0x8000u;
            unsigned u2 = __float_as_uint(acc[mt].z) + 0x8000u;
            unsigned u3 = __float_as_uint(acc[mt].w) + 0x8000u;
            pk[2 * mt]     = __builtin_amdgcn_perm(u1, u0, 0x07060302u);
            pk[2 * mt + 1] = __builtin_amdgcn_perm(u3, u2, 0x07060302u);
        }
    }

    // chunk ll partial: telescoped  log(S_end) - log(S_pre) - CLEN*ln(64)
    if (q == 0) {
        float ll = __logf(s_end) - __logf(s_pre) - (float)CLEN * LN64;
        atomicAdd(&out_ll[bg * 16 + n], ll);
    }
}

extern "C" void kernel_launch(void* const* d_in, const int* in_sizes, int n_in,
                              void* d_out, int out_size, void* d_ws, size_t ws_size,
                              hipStream_t stream) {
    const float* x = (const float*)d_in[0];   // [B, T, EMIT] one-hot fp32
    const float* I = (const float*)d_in[1];   // [NS]
    const float* A = (const float*)d_in[2];   // [NS, NS]
    const float* B = (const float*)d_in[3];   // [EMIT, NS]
    float* out = (float*)d_out;               // alpha_f [B*NS] ++ loglik [B]

    unsigned char* obsG = (unsigned char*)d_ws;   // [BG][16][TLEN] bytes = 1 MiB

    decode_onehot<<<(BATCH * TLEN * 16) / 256, 256, 0, stream>>>(
        (const floatx4*)x, obsG, out + BATCH * NS);
    hmm_scan<<<BG * NCHUNK, 64, 0, stream>>>(A, B, I, obsG, out, out + BATCH * NS);
}

// Round 8
// 401.925 us; speedup vs baseline: 1.0497x; 1.0497x over previous
//
#include <hip/hip_runtime.h>

// HMM scaled forward — streaming decode + prep (fragment precompute) + MFMA scan.
//   BATCH=128, T=8192, N_STATES=128, EMIT=64
// decode_onehot: 256 MiB one-hot -> obsG[bg][n][t] bytes (1 MiB), HBM-bound.
// prep: one WG converts A into bf16 MFMA fragments in EXACT lane order
//   (afG[lane][mt*4+kf], 32 KB, L2-resident broadcast for all scan waves) and
//   B into the padded bf16 table (16.9 KB); zeroes out_ll.
// hmm_scan: one wave per (batch-group of 16, chunk of 32 + 8 warmup).
//   Setup is now ~55 vectorized VMEM ops/lane; loop: permuted-K fragments make
//   the packed MFMA D-output directly the next step's B-fragment — alpha never
//   leaves registers; telescoped normalization (2-3 shfl reductions/chunk).

#define BATCH 128
#define TLEN 8192
#define NS 128
#define EMIT 64
#define NCHUNK 256
#define CLEN (TLEN / NCHUNK)   // 32
#define WARM 8
#define BG 8                   // batch groups of 16
#define BSTR 132               // B-table row stride (bf16 elems)
#define LN64 4.158883083359672f

typedef __attribute__((ext_vector_type(8))) short short8;
typedef __attribute__((ext_vector_type(4))) float floatx4;
typedef __attribute__((ext_vector_type(4))) unsigned int uintx4;

__device__ __forceinline__ unsigned f2bf(float f) {
    return (__float_as_uint(f) + 0x8000u) >> 16;   // round-half-up to bf16
}

// decode 256 MiB one-hot -> obsG[bg][n][t] bytes (1 MiB)
__global__ __launch_bounds__(256) void decode_onehot(
        const floatx4* __restrict__ x, unsigned char* __restrict__ obsG) {
    int base = blockIdx.x * 512 + threadIdx.x;
    #pragma unroll
    for (int h = 0; h < 2; ++h) {
        int i = base + h * 256;                    // BATCH*TLEN*16 float4s
        floatx4 v = __builtin_nontemporal_load(&x[i]);
        float s = v.x + v.y + v.z + v.w;
        if (s > 0.5f) {
            int e = (v.y > 0.5f) ? 1 : (v.z > 0.5f) ? 2 : (v.w > 0.5f) ? 3 : 0;
            int elem = (i << 2) + e;
            int row = elem >> 6;                   // b*TLEN + t
            int col = elem & 63;                   // emission symbol
            int b = row >> 13;
            int t = row & (TLEN - 1);
            obsG[(b >> 4) * (16 * TLEN) + (b & 15) * TLEN + t] = (unsigned char)col;
        }
    }
}

// one WG: A -> bf16 fragments in lane order; B -> padded bf16 table; zero ll
__global__ __launch_bounds__(256) void prep(
        const float* __restrict__ Amat, const float* __restrict__ Bmat,
        short* __restrict__ afG,              // [64][32] short8 = 32 KB
        unsigned short* __restrict__ Bbf,     // [EMIT*BSTR] = 16896 B
        float* __restrict__ out_ll) {
    int tid = threadIdx.x;
    if (tid < BATCH) out_ll[tid] = 0.f;
    // A fragments: lane = tid&63 handles frags (tid>>6)*8 .. +8
    int lane = tid & 63, g = tid >> 6;
    int n = lane & 15, q = lane >> 4;
    for (int f = g * 8; f < g * 8 + 8; ++f) {
        int mt = f >> 2, kf = f & 3;
        short8 v;
        #pragma unroll
        for (int j = 0; j < 8; ++j) {
            int u = 32 * kf + 8 * q + j;
            int sk = 32 * (u >> 5) + 16 * ((u >> 2) & 1)
                   + 4 * ((u >> 3) & 3) + (u & 3);
            v[j] = (short)f2bf(Amat[sk * NS + 16 * mt + n]);
        }
        *(short8*)(afG + (lane * 32 + f) * 8) = v;
    }
    // B table: bf16(64*B), padded stride
    for (int i = tid; i < EMIT * BSTR; i += 256) {
        int e = i / BSTR, col = i - e * BSTR;
        Bbf[i] = (col < NS) ? (unsigned short)f2bf(64.0f * Bmat[e * NS + col]) : 0;
    }
}

__global__ __launch_bounds__(64) void hmm_scan(
        const short* __restrict__ afG,
        const uintx4* __restrict__ Bbf4,   // padded bf16 B-table as dword4s
        const float* __restrict__ Ivec,
        const unsigned char* __restrict__ obsG,
        float* __restrict__ out_alpha,    // [BATCH][NS]
        float* __restrict__ out_ll)       // [BATCH]
{
    __shared__ uintx4 Bl4[(EMIT * BSTR) / 8];     // 16896 B: bf16(64*B)

    const int lane = threadIdx.x;
    const int n = lane & 15;              // batch within group (D col)
    const int q = lane >> 4;              // quad
    const int bg = blockIdx.x >> 8;       // / NCHUNK
    const int c = blockIdx.x & (NCHUNK - 1);
    const bool first = (c == 0);
    const bool lastc = (c == NCHUNK - 1);
    const int steps = first ? CLEN : (CLEN + WARM);
    const int t0 = first ? 0 : c * CLEN - WARM;

    // this lane's obs bytes -> 10 dwords (issue first, longest latency)
    const unsigned char* orow = obsG + bg * (16 * TLEN) + n * TLEN;
    unsigned ow[10];
    if (first) {                          // t0==0: 32 bytes, 16B aligned
        uintx4 a = *(const uintx4*)(orow);
        uintx4 b = *(const uintx4*)(orow + 16);
        ow[0] = a.x; ow[1] = a.y; ow[2] = a.z; ow[3] = a.w;
        ow[4] = b.x; ow[5] = b.y; ow[6] = b.z; ow[7] = b.w;
        ow[8] = 0; ow[9] = 0;
    } else {                              // t0 = 32c-8: 8B then 16B aligned
        uint2 a = *(const uint2*)(orow + t0);
        uintx4 b = *(const uintx4*)(orow + t0 + 8);
        uintx4 d = *(const uintx4*)(orow + t0 + 24);
        ow[0] = a.x; ow[1] = a.y;
        ow[2] = b.x; ow[3] = b.y; ow[4] = b.z; ow[5] = b.w;
        ow[6] = d.x; ow[7] = d.y; ow[8] = d.z; ow[9] = d.w;
    }

    // stage bf16 B-table into LDS with b128 copies (1056 dword4s / 64 lanes)
    #pragma unroll
    for (int i = 0; i < 16; ++i)
        Bl4[lane + 64 * i] = Bbf4[lane + 64 * i];
    if (lane < 32) Bl4[lane + 1024] = Bbf4[lane + 1024];

    // A fragments: 32x global_load_dwordx4 of precomputed bf16 (L2-hot)
    short8 af[8][4];
    {
        const short8* ap = (const short8*)(afG + lane * 256);
        #pragma unroll
        for (int mt = 0; mt < 8; ++mt)
            #pragma unroll
            for (int kf = 0; kf < 4; ++kf)
                af[mt][kf] = ap[mt * 4 + kf];
    }
    __syncthreads();   // Bl ready

    const unsigned short* Bl = (const unsigned short*)Bl4;

    // loop-carried packed alpha (bf16 pairs); init uniform for warmup
    unsigned pk[16];
    #pragma unroll
    for (int i = 0; i < 16; ++i) pk[i] = 0x3C003C00u;   // bf16(1/128) x2

    float s_pre = 1.0f, s_penult = 1.0f, s_end = 1.0f;

    for (int it = 0; it < steps; ++it) {
        floatx4 acc[8];
        if (first && it == 0) {
            // t==0: R := I (exact init), alpha0 = 64B[o] * I
            #pragma unroll
            for (int mt = 0; mt < 8; ++mt)
                acc[mt] = *(const floatx4*)(Ivec + 16 * mt + 4 * q);
        } else {
            short8 bf[4];
            #pragma unroll
            for (int kf = 0; kf < 4; ++kf) {
                uintx4 u4 = {pk[4 * kf], pk[4 * kf + 1], pk[4 * kf + 2], pk[4 * kf + 3]};
                bf[kf] = __builtin_bit_cast(short8, u4);
            }
            #pragma unroll
            for (int mt = 0; mt < 8; ++mt) {
                floatx4 a = {0.f, 0.f, 0.f, 0.f};
                #pragma unroll
                for (int kf = 0; kf < 4; ++kf)
                    a = __builtin_amdgcn_mfma_f32_16x16x32_bf16(af[mt][kf], bf[kf], a, 0, 0, 0);
                acc[mt] = a;
            }
        }

        // emission multiply (table holds 64*B)
        int o = (ow[it >> 2] >> ((it & 3) * 8)) & 0xFF;
        int eb = o * BSTR;
        #pragma unroll
        for (int mt = 0; mt < 8; ++mt) {
            const unsigned* ep = (const unsigned*)(Bl + eb + 16 * mt + 4 * q);
            unsigned d0 = ep[0], d1 = ep[1];
            acc[mt].x *= __uint_as_float(d0 << 16);
            acc[mt].y *= __uint_as_float(d0 & 0xFFFF0000u);
            acc[mt].z *= __uint_as_float(d1 << 16);
            acc[mt].w *= __uint_as_float(d1 & 0xFFFF0000u);
        }

        // rare per-chunk reductions (wave-uniform branch)
        bool need_red = (it == steps - 1) || (!first && it == WARM - 1) ||
                        (lastc && it == steps - 2);
        if (need_red) {
            float zz = 0.f;
            #pragma unroll
            for (int mt = 0; mt < 8; ++mt)
                zz += (acc[mt].x + acc[mt].y) + (acc[mt].z + acc[mt].w);
            zz += __shfl_xor(zz, 16, 64);
            zz += __shfl_xor(zz, 32, 64);      // S-bar per batch, all q-lanes
            if (it == steps - 1) s_end = zz;
            else if (lastc && it == steps - 2) s_penult = zz;
            else s_pre = zz;
        }

        if (lastc && it == steps - 1) {
            // alpha_f = alpha-bar_{T-1} / (64 * S-bar_{T-2})
            float inv = 1.0f / (64.0f * s_penult);
            #pragma unroll
            for (int mt = 0; mt < 8; ++mt) {
                floatx4 o4;
                o4.x = acc[mt].x * inv; o4.y = acc[mt].y * inv;
                o4.z = acc[mt].z * inv; o4.w = acc[mt].w * inv;
                *(floatx4*)(out_alpha + (bg * 16 + n) * NS + 16 * mt + 4 * q) = o4;
            }
        }

        // pack to bf16 pairs: directly forms next step's B-fragments
        #pragma unroll
        for (int mt = 0; mt < 8; ++mt) {
            unsigned u0 = __float_as_uint(acc[mt].x) + 0x8000u;
            unsigned u1 = __float_as_uint(acc[mt].y) + 0x8000u;
            unsigned u2 = __float_as_uint(acc[mt].z) + 0x8000u;
            unsigned u3 = __float_as_uint(acc[mt].w) + 0x8000u;
            pk[2 * mt]     = __builtin_amdgcn_perm(u1, u0, 0x07060302u);
            pk[2 * mt + 1] = __builtin_amdgcn_perm(u3, u2, 0x07060302u);
        }
    }

    // chunk ll partial: telescoped  log(S_end) - log(S_pre) - CLEN*ln(64)
    if (q == 0) {
        float ll = __logf(s_end) - __logf(s_pre) - (float)CLEN * LN64;
        atomicAdd(&out_ll[bg * 16 + n], ll);
    }
}

extern "C" void kernel_launch(void* const* d_in, const int* in_sizes, int n_in,
                              void* d_out, int out_size, void* d_ws, size_t ws_size,
                              hipStream_t stream) {
    const float* x = (const float*)d_in[0];   // [B, T, EMIT] one-hot fp32
    const float* I = (const float*)d_in[1];   // [NS]
    const float* A = (const float*)d_in[2];   // [NS, NS]
    const float* B = (const float*)d_in[3];   // [EMIT, NS]
    float* out = (float*)d_out;               // alpha_f [B*NS] ++ loglik [B]

    unsigned char* obsG = (unsigned char*)d_ws;             // 1 MiB
    short* afG = (short*)((char*)d_ws + (1 << 20));         // 32 KB
    unsigned short* Bbf = (unsigned short*)((char*)d_ws + (1 << 20) + (32 << 10));

    decode_onehot<<<(BATCH * TLEN * 16) / 512, 256, 0, stream>>>(
        (const floatx4*)x, obsG);
    prep<<<1, 256, 0, stream>>>(A, B, afG, Bbf, out + BATCH * NS);
    hmm_scan<<<BG * NCHUNK, 64, 0, stream>>>(
        afG, (const uintx4*)Bbf, I, obsG, out, out + BATCH * NS);
}